// Round 4
// 455.636 us; speedup vs baseline: 1.0269x; 1.0269x over previous
//
#include <hip/hip_runtime.h>

// Problem constants (from reference setup_inputs):
//   B=8, T=4096, x0:[8,1024,4096] f32, x1:[8,768,4096] f32
//   BC=256, RC=64, NB0=4, NB1=3, TB=7, EPS=1e-5, LOWEST=0
#define B_SZ 8
#define T_SZ 4096
#define BC 256
#define RC 64
#define NB0 4
#define NB1 3
#define TB 7
#define ROWS0 (B_SZ * 1024)            // 8192 rows in x0
#define ROWS1 (B_SZ * 768)             // 6144 rows in x1
#define ROWS_TOTAL (ROWS0 + ROWS1)     // 14336
#define X0_ELEMS (33554432ull)         // 8*1024*4096

// Native vector type: __builtin_nontemporal_store rejects HIP_vector_type
// (float4 is a class); ext_vector_type is accepted and bit-identical.
typedef float vfloat4 __attribute__((ext_vector_type(4)));

// ---------------------------------------------------------------------------
// Kernel 1: per-row sum over time -> rowsum[row]. No atomics, no memset.
// rowsum lives in the first 56 KiB of d_out (scratch); it is fully consumed
// by score_kernel before scale_kernel overwrites out. Workspace footprint
// stays at 56 KiB (<= the 64 KiB proven safe by the baseline session).
// One wave (64 lanes) per row of 4096 floats = 1024 float4 = 16 float4/lane.
// blockDim = 256 -> 4 rows per block; grid = 14336/4 = 3584 blocks.
// ---------------------------------------------------------------------------
__global__ __launch_bounds__(256) void rowsum_kernel(const float* __restrict__ x0,
                                                     const float* __restrict__ x1,
                                                     float* __restrict__ rowsum) {
    const int gtid = blockIdx.x * 256 + threadIdx.x;
    const int wave = gtid >> 6;        // global row index
    const int lane = threadIdx.x & 63;

    const float4* src = (wave < ROWS0)
        ? (const float4*)(x0 + (size_t)wave * T_SZ)
        : (const float4*)(x1 + (size_t)(wave - ROWS0) * T_SZ);

    float sum = 0.0f;
#pragma unroll
    for (int it = 0; it < 16; ++it) {
        float4 v = src[it * 64 + lane];
        sum += (v.x + v.y) + (v.z + v.w);
    }
    // wave-64 butterfly reduce
#pragma unroll
    for (int off = 32; off > 0; off >>= 1)
        sum += __shfl_down(sum, off, 64);

    if (lane == 0)
        rowsum[wave] = sum;
}

// ---------------------------------------------------------------------------
// Kernel 2: raw attention scores, one block per head k (grid=7, 256 thr).
// Each block redundantly computes gap (2048 sums of 7 rowsums) and
// h = relu(BN(gap @ W1 + b1)) in LDS (cheap), then its own k's scores:
//   scores[k,b,c] = h[b,:] @ Wh[k,:,c] + bh[k,c]
// Register-blocked over b: each Wh element is loaded ONCE and used 8x.
// Per thread: ~64 Wh loads + 512 FMA (vs 3584 latency-bound loads in the
// baseline's single-block attn kernel).
// Softmax is NOT done here (needs all k) -- folded into kernel 3.
// ---------------------------------------------------------------------------
__global__ __launch_bounds__(256) void score_kernel(const float* __restrict__ rowsum,
                                                    const float* __restrict__ W1,
                                                    const float* __restrict__ b1,
                                                    const float* __restrict__ gamma,
                                                    const float* __restrict__ beta,
                                                    const float* __restrict__ Wh,
                                                    const float* __restrict__ bh,
                                                    float* __restrict__ scores) {
    __shared__ float s_gap[B_SZ * BC];   // 8 KiB
    __shared__ float s_h[B_SZ * RC];     // 2 KiB
    const int tid = threadIdx.x;
    const int k = blockIdx.x;

    // gap[b][c] = (sum over the 7 block-rows of (b,c)) / T
#pragma unroll
    for (int p = tid; p < B_SZ * BC; p += 256) {
        const int b = p >> 8;
        const int c = p & 255;
        float s = 0.0f;
#pragma unroll
        for (int blk = 0; blk < NB0; ++blk)
            s += rowsum[b * 1024 + blk * 256 + c];
#pragma unroll
        for (int blk = 0; blk < NB1; ++blk)
            s += rowsum[ROWS0 + b * 768 + blk * 256 + c];
        s_gap[p] = s * (1.0f / (float)T_SZ);
    }
    __syncthreads();

    // h[b][r] = relu((gap[b,:] @ W1[:,r] + b1[r]) * gamma[r]/sqrt(1+eps) + beta[r])
    const float bnscale = rsqrtf(1.0f + 1e-5f);
#pragma unroll
    for (int p = tid; p < B_SZ * RC; p += 256) {
        const int b = p >> 6;
        const int r = p & 63;
        float acc = 0.0f;
#pragma unroll 8
        for (int c = 0; c < BC; ++c)
            acc = fmaf(s_gap[b * BC + c], W1[c * RC + r], acc);
        acc += b1[r];
        acc = acc * (gamma[r] * bnscale) + beta[r];
        s_h[p] = fmaxf(acc, 0.0f);
    }
    __syncthreads();

    // thread tid owns channel c=tid for all 8 b of this block's k
    float acc[B_SZ];
    const float bias = bh[k * BC + tid];
#pragma unroll
    for (int b = 0; b < B_SZ; ++b) acc[b] = bias;
    for (int r = 0; r < RC; ++r) {
        const float w = Wh[(k * RC + r) * BC + tid];   // coalesced, loaded once
#pragma unroll
        for (int b = 0; b < B_SZ; ++b)
            acc[b] = fmaf(s_h[b * RC + r], w, acc[b]); // LDS broadcast read
    }
#pragma unroll
    for (int b = 0; b < B_SZ; ++b)
        scores[(k * B_SZ + b) * BC + tid] = acc[b];
}

// ---------------------------------------------------------------------------
// Kernel 3: softmax over k (7 uniform scalar loads, ~free) + scale the row.
// One block per row, 256 threads x 4 float4 = 4096 floats.
// Nontemporal stores: keep x0/x1 resident in L3 (235 MB < 256 MiB) so the
// second read of the inputs is an L3 hit instead of HBM.
// d_out = [out0 flat (33.5M) | out1 flat (25.2M)]
// ---------------------------------------------------------------------------
__global__ __launch_bounds__(256) void scale_kernel(const float* __restrict__ x0,
                                                    const float* __restrict__ x1,
                                                    const float* __restrict__ scores,
                                                    float* __restrict__ out) {
    const int row = blockIdx.x;
    const vfloat4* src;
    vfloat4* dst;
    int b, c, ksel;
    if (row < ROWS0) {
        b = row >> 10;
        const int ch = row & 1023;
        ksel = ch >> 8;
        c = ch & 255;
        src = (const vfloat4*)(x0 + (size_t)row * T_SZ);
        dst = (vfloat4*)(out + (size_t)row * T_SZ);
    } else {
        const int r = row - ROWS0;
        b = (int)((unsigned)r / 768u);
        const int ch = r - b * 768;
        ksel = NB0 + (ch >> 8);
        c = ch & 255;
        src = (const vfloat4*)(x1 + (size_t)r * T_SZ);
        dst = (vfloat4*)(out + X0_ELEMS + (size_t)r * T_SZ);
    }

    // softmax over the 7 heads for this (b,c); block-uniform -> scalar loads.
    // NOTE: keep the selected exp in a scalar via select (runtime-indexed
    // arrays would spill to scratch -- rule #20).
    float sc[TB];
    float mx = -1e30f;
#pragma unroll
    for (int kk = 0; kk < TB; ++kk) {
        sc[kk] = scores[(kk * B_SZ + b) * BC + c];
        mx = fmaxf(mx, sc[kk]);
    }
    float sum = 0.0f, esel = 0.0f;
#pragma unroll
    for (int kk = 0; kk < TB; ++kk) {
        const float e = __expf(sc[kk] - mx);
        sum += e;
        esel = (kk == ksel) ? e : esel;
    }
    const float a = esel / sum;   // LOWEST=0 -> no affine remap

    const int tid = threadIdx.x;
#pragma unroll
    for (int it = 0; it < 4; ++it) {
        vfloat4 v = src[it * 256 + tid];
        v *= a;
        __builtin_nontemporal_store(v, &dst[it * 256 + tid]);
    }
}

extern "C" void kernel_launch(void* const* d_in, const int* in_sizes, int n_in,
                              void* d_out, int out_size, void* d_ws, size_t ws_size,
                              hipStream_t stream) {
    const float* x0    = (const float*)d_in[0];
    const float* x1    = (const float*)d_in[1];
    const float* W1    = (const float*)d_in[2];
    const float* b1    = (const float*)d_in[3];
    const float* gamma = (const float*)d_in[4];
    const float* beta  = (const float*)d_in[5];
    const float* Wh    = (const float*)d_in[6];
    const float* bh    = (const float*)d_in[7];
    float* out = (float*)d_out;

    // rowsum scratch lives in d_out (first 14336 floats); fully consumed by
    // score_kernel before scale_kernel overwrites all of out (stream order).
    float* rowsum = out;
    // scores in workspace: 14336 floats = 56 KiB <= baseline-proven 64 KiB.
    float* scores = (float*)d_ws;

    rowsum_kernel<<<ROWS_TOTAL / 4, 256, 0, stream>>>(x0, x1, rowsum);
    score_kernel<<<TB, 256, 0, stream>>>(rowsum, W1, b1, gamma, beta, Wh, bh, scores);
    scale_kernel<<<ROWS_TOTAL, 256, 0, stream>>>(x0, x1, scores, out);
}

// Round 5
// 449.094 us; speedup vs baseline: 1.0418x; 1.0146x over previous
//
#include <hip/hip_runtime.h>

// Problem constants (from reference setup_inputs):
//   B=8, T=4096, x0:[8,1024,4096] f32, x1:[8,768,4096] f32
//   BC=256, RC=64, NB0=4, NB1=3, TB=7, EPS=1e-5, LOWEST=0
#define B_SZ 8
#define T_SZ 4096
#define BC 256
#define RC 64
#define NB0 4
#define NB1 3
#define TB 7
#define ROWS0 (B_SZ * 1024)            // 8192 rows in x0
#define ROWS1 (B_SZ * 768)             // 6144 rows in x1
#define ROWS_TOTAL (ROWS0 + ROWS1)     // 14336
#define X0_ELEMS (33554432ull)         // 8*1024*4096

// Native vector type: __builtin_nontemporal_{load,store} rejects
// HIP_vector_type (float4 is a class); ext_vector_type is bit-identical.
typedef float vfloat4 __attribute__((ext_vector_type(4)));

// ---------------------------------------------------------------------------
// Kernel 1: per-row sum over time -> rowsum[row]. No atomics, no memset.
// rowsum lives in the first 56 KiB of d_out (scratch); fully consumed by
// att_kernel before scale_kernel overwrites out (stream order guarantees).
// One wave per row: 16 x (1 KiB contiguous per wave) = 16 KiB row.
// ---------------------------------------------------------------------------
__global__ __launch_bounds__(256) void rowsum_kernel(const float* __restrict__ x0,
                                                     const float* __restrict__ x1,
                                                     float* __restrict__ rowsum) {
    const int gtid = blockIdx.x * 256 + threadIdx.x;
    const int wave = gtid >> 6;        // global row index
    const int lane = threadIdx.x & 63;

    const float4* src = (wave < ROWS0)
        ? (const float4*)(x0 + (size_t)wave * T_SZ)
        : (const float4*)(x1 + (size_t)(wave - ROWS0) * T_SZ);

    float sum = 0.0f;
#pragma unroll
    for (int it = 0; it < 16; ++it) {
        float4 v = src[it * 64 + lane];
        sum += (v.x + v.y) + (v.z + v.w);
    }
#pragma unroll
    for (int off = 32; off > 0; off >>= 1)
        sum += __shfl_down(sum, off, 64);

    if (lane == 0)
        rowsum[wave] = sum;
}

// ---------------------------------------------------------------------------
// Kernel 2: FINAL attention weights, one block per batch b (grid=8, 256 thr).
//   gap[c]  = (sum of 7 block-row sums)/T               (tid = c)
//   h[r]    = relu(BN(gap @ W1 + b1))                   (tid < 64)
//   sc[k]   = h @ Wh[k,:,c] + bh[k,c]   for all 7 k     (tid = c)
//   att[b,k,c] = softmax_k(sc)          (LOWEST=0 -> no remap)
// Wh read: 8 blocks x 448 KB = 3.6 MB total, L2/L3-resident. 7 independent
// FMA chains (k inner) give ILP; ~5 us total for the whole kernel.
// ---------------------------------------------------------------------------
__global__ __launch_bounds__(256) void att_kernel(const float* __restrict__ rowsum,
                                                  const float* __restrict__ W1,
                                                  const float* __restrict__ b1,
                                                  const float* __restrict__ gamma,
                                                  const float* __restrict__ beta,
                                                  const float* __restrict__ Wh,
                                                  const float* __restrict__ bh,
                                                  float* __restrict__ att) {
    __shared__ float s_gap[BC];
    __shared__ float s_h[RC];
    const int tid = threadIdx.x;
    const int b = blockIdx.x;

    // gap for this b (tid = channel c)
    float s = 0.0f;
#pragma unroll
    for (int blk = 0; blk < NB0; ++blk)
        s += rowsum[b * 1024 + blk * 256 + tid];
#pragma unroll
    for (int blk = 0; blk < NB1; ++blk)
        s += rowsum[ROWS0 + b * 768 + blk * 256 + tid];
    s_gap[tid] = s * (1.0f / (float)T_SZ);
    __syncthreads();

    // h[r] for r = tid < 64 (1 of 4 waves active; 256-FMA dot, trivial)
    if (tid < RC) {
        const float bnscale = rsqrtf(1.0f + 1e-5f);
        float acc = 0.0f;
#pragma unroll 8
        for (int c = 0; c < BC; ++c)
            acc = fmaf(s_gap[c], W1[c * RC + tid], acc);
        acc += b1[tid];
        acc = acc * (gamma[tid] * bnscale) + beta[tid];
        s_h[tid] = fmaxf(acc, 0.0f);
    }
    __syncthreads();

    // scores for channel c = tid, all 7 heads; then softmax over k.
    float sc[TB];
#pragma unroll
    for (int k = 0; k < TB; ++k)
        sc[k] = bh[k * BC + tid];
    for (int r = 0; r < RC; ++r) {
        const float hr = s_h[r];                       // LDS broadcast
#pragma unroll
        for (int k = 0; k < TB; ++k)
            sc[k] = fmaf(Wh[(k * RC + r) * BC + tid], hr, sc[k]);
    }
    float mx = -1e30f;
#pragma unroll
    for (int k = 0; k < TB; ++k) mx = fmaxf(mx, sc[k]);
    float sum = 0.0f;
#pragma unroll
    for (int k = 0; k < TB; ++k) { sc[k] = __expf(sc[k] - mx); sum += sc[k]; }
    const float inv = 1.0f / sum;
#pragma unroll
    for (int k = 0; k < TB; ++k)
        att[(b * TB + k) * BC + tid] = sc[k] * inv;
}

// ---------------------------------------------------------------------------
// Kernel 3: scale each row by its (precomputed) attention scalar.
// 4 rows per block, one wave per row (same proven pattern as rowsum).
// Nontemporal LOADS on x: last use -- consumed lines become preferred
// eviction victims, protecting the not-yet-read tail of x in L3 from the
// output write-allocations. Nontemporal STORES: output is write-once.
// d_out = [out0 flat (33.5M) | out1 flat (25.2M)]
// ---------------------------------------------------------------------------
__global__ __launch_bounds__(256) void scale_kernel(const float* __restrict__ x0,
                                                    const float* __restrict__ x1,
                                                    const float* __restrict__ att,
                                                    float* __restrict__ out) {
    const int row = blockIdx.x * 4 + (threadIdx.x >> 6);
    const int lane = threadIdx.x & 63;

    const vfloat4* src;
    vfloat4* dst;
    float a;
    if (row < ROWS0) {
        const int b = row >> 10;
        const int ch = row & 1023;
        a = att[(b * TB + (ch >> 8)) * BC + (ch & 255)];
        src = (const vfloat4*)(x0 + (size_t)row * T_SZ);
        dst = (vfloat4*)(out + (size_t)row * T_SZ);
    } else {
        const int r = row - ROWS0;
        const int b = (int)((unsigned)r / 768u);
        const int ch = r - b * 768;
        a = att[(b * TB + NB0 + (ch >> 8)) * BC + (ch & 255)];
        src = (const vfloat4*)(x1 + (size_t)r * T_SZ);
        dst = (vfloat4*)(out + X0_ELEMS + (size_t)r * T_SZ);
    }

#pragma unroll
    for (int it = 0; it < 16; ++it) {
        vfloat4 v = __builtin_nontemporal_load(&src[it * 64 + lane]);
        v *= a;
        __builtin_nontemporal_store(v, &dst[it * 64 + lane]);
    }
}

extern "C" void kernel_launch(void* const* d_in, const int* in_sizes, int n_in,
                              void* d_out, int out_size, void* d_ws, size_t ws_size,
                              hipStream_t stream) {
    const float* x0    = (const float*)d_in[0];
    const float* x1    = (const float*)d_in[1];
    const float* W1    = (const float*)d_in[2];
    const float* b1    = (const float*)d_in[3];
    const float* gamma = (const float*)d_in[4];
    const float* beta  = (const float*)d_in[5];
    const float* Wh    = (const float*)d_in[6];
    const float* bh    = (const float*)d_in[7];
    float* out = (float*)d_out;

    // rowsum scratch lives in d_out (first 14336 floats); fully consumed by
    // att_kernel before scale_kernel overwrites all of out (stream order).
    float* rowsum = out;
    // att in workspace: 7*8*256 = 14336 floats = 56 KiB (<= proven 64 KiB).
    float* att = (float*)d_ws;

    rowsum_kernel<<<ROWS_TOTAL / 4, 256, 0, stream>>>(x0, x1, rowsum);
    att_kernel<<<B_SZ, 256, 0, stream>>>(rowsum, W1, b1, gamma, beta, Wh, bh, att);
    scale_kernel<<<ROWS_TOTAL / 4, 256, 0, stream>>>(x0, x1, att, out);
}